// Round 4
// baseline (34328.394 us; speedup 1.0000x reference)
//
#include <hip/hip_runtime.h>

typedef __bf16 bf16;
typedef __bf16 v8bf __attribute__((ext_vector_type(8)));
typedef __bf16 v4bf __attribute__((ext_vector_type(4)));
typedef float  v4f  __attribute__((ext_vector_type(4)));

// B=128, T=256, D=H=V=1024, S=128. All GEMM K dims = 1024.

static __device__ __forceinline__ float fast_tanh(float x) {
  x = fminf(fmaxf(x, -10.f), 10.f);
  float e = __expf(2.f * x);
  return (e - 1.f) * __builtin_amdgcn_rcpf(e + 1.f);
}
static __device__ __forceinline__ float fast_sigmoid(float x) {
  return __builtin_amdgcn_rcpf(1.f + __expf(-x));
}

// ---------------------------------------------------------------------------
// MFMA-fragment packing (HW-verified rounds 1/3): element (r,k) of X[R][1024]:
//   off = (((r>>4)*32 + (k>>5))*64 + ((k>>3)&3)*16 + (r&15))*8 + (k&7)
// lane-linear 16B chunks -> global_load_dwordx4 straight into MFMA, no LDS.
// ---------------------------------------------------------------------------
static __device__ __forceinline__ size_t packOff(int r, int k) {
  return ((size_t)((r >> 4) * 32 + (k >> 5)) * 64 + ((k >> 3) & 3) * 16 + (r & 15)) * 8 + (k & 7);
}

template<int NKS>
static __device__ __forceinline__ void gemmTile(const bf16* __restrict__ Ap,
                                                const bf16* __restrict__ Bp,
                                                int m0, int n0, int ks0,
                                                v4f acc[2][2]) {
  const int lane = threadIdx.x & 63;
  const int w = threadIdx.x >> 6;
  const int wr = w >> 1, wc = w & 1;
  const bf16* a0p = Ap + (((size_t)((m0 >> 4) + wr * 2) * 32 + ks0) * 64 + lane) * 8;
  const bf16* b0p = Bp + (((size_t)((n0 >> 4) + wc * 2) * 32 + ks0) * 64 + lane) * 8;
#pragma unroll 8
  for (int ks = 0; ks < NKS; ks++) {
    v8bf a0 = *(const v8bf*)(a0p);
    v8bf a1 = *(const v8bf*)(a0p + 16384);   // next 16-row block: 32*64*8
    v8bf b0 = *(const v8bf*)(b0p);
    v8bf b1 = *(const v8bf*)(b0p + 16384);
    a0p += 512; b0p += 512;
    acc[0][0] = __builtin_amdgcn_mfma_f32_16x16x32_bf16(a0, b0, acc[0][0], 0, 0, 0);
    acc[0][1] = __builtin_amdgcn_mfma_f32_16x16x32_bf16(a0, b1, acc[0][1], 0, 0, 0);
    acc[1][0] = __builtin_amdgcn_mfma_f32_16x16x32_bf16(a1, b0, acc[1][0], 0, 0, 0);
    acc[1][1] = __builtin_amdgcn_mfma_f32_16x16x32_bf16(a1, b1, acc[1][1], 0, 0, 0);
  }
}

// C/D layout (HW-verified): col = lane&15, row = (lane>>4)*4 + i
static __device__ __forceinline__ void storeTileF32(float* C, int ldc,
                                                    int m0, int n0, v4f acc[2][2]) {
  const int lane = threadIdx.x & 63, w = threadIdx.x >> 6;
  const int wr = w >> 1, wc = w & 1;
  const int mB = m0 + wr * 32 + (lane >> 4) * 4;
  const int nB = n0 + wc * 32 + (lane & 15);
#pragma unroll
  for (int mf = 0; mf < 2; mf++)
#pragma unroll
    for (int nf = 0; nf < 2; nf++)
#pragma unroll
      for (int i = 0; i < 4; i++)
        C[(size_t)(mB + mf * 16 + i) * ldc + nB + nf * 16] = acc[mf][nf][i];
}

// ---------------------------------------------------------------------------
// Setup kernels (unchanged from round 3, HW-verified)
// ---------------------------------------------------------------------------
__global__ __launch_bounds__(256) void kPack(const float* __restrict__ src, int ld,
                                             bf16* __restrict__ dst, int nTh) {
  int th = blockIdx.x * 256 + threadIdx.x;
  if (th >= nTh) return;
  int rb = th >> 11, ks = (th >> 6) & 31, l = th & 63;
  int r = rb * 16 + (l & 15);
  int k = ks * 32 + ((l >> 4) & 3) * 8;
  const float* s = src + (size_t)r * ld + k;
  v4f v0 = *(const v4f*)(s);
  v4f v1 = *(const v4f*)(s + 4);
  v8bf o;
#pragma unroll
  for (int e = 0; e < 4; e++) { o[e] = (bf16)v0[e]; o[4 + e] = (bf16)v1[e]; }
  *(v8bf*)(dst + (size_t)th * 8) = o;
}

__global__ __launch_bounds__(256) void kCast4(const float* __restrict__ src,
                                              bf16* __restrict__ dst, int n4) {
  int i = blockIdx.x * 256 + threadIdx.x;
  if (i < n4) {
    v4f v = ((const v4f*)src)[i];
    ((v4bf*)dst)[i] = __builtin_convertvector(v, v4bf);
  }
}

// bias sum + zero y0 + zero grid-barrier counter (re-run every call: ws re-poisoned)
__global__ __launch_bounds__(256) void kPrep(const float* rnn_b_ih, const float* rnn_b_hh,
                                             float* bsum, bf16* y_b16p, unsigned* bar) {
  int th = blockIdx.x * 256 + threadIdx.x;
  if (th < 16384) {
    v8bf z = {};
    ((v8bf*)y_b16p)[th] = z;
  } else if (th < 17408) {
    int j = th - 16384;
    bsum[j] = rnn_b_ih[j] + rnn_b_hh[j];
  } else if (th == 17408) {
    *bar = 0u;
  }
}

// tw = tanh(h @ w_h_a^T) -> bf16 linear (M=32768, N=1024)
__global__ __launch_bounds__(256) void kGemmTW(const bf16* __restrict__ Ap,
                                               const bf16* __restrict__ Bp,
                                               bf16* __restrict__ C) {
  const int nt = blockIdx.x & 15, mt = blockIdx.x >> 4;
  v4f acc[2][2] = {};
  gemmTile<32>(Ap, Bp, mt * 64, nt * 64, 0, acc);
  const int lane = threadIdx.x & 63, w = threadIdx.x >> 6;
  const int wr = w >> 1, wc = w & 1;
  const int mB = mt * 64 + wr * 32 + (lane >> 4) * 4;
  const int nB = nt * 64 + wc * 32 + (lane & 15);
#pragma unroll
  for (int mf = 0; mf < 2; mf++)
#pragma unroll
    for (int nf = 0; nf < 2; nf++)
#pragma unroll
      for (int i = 0; i < 4; i++)
        C[(size_t)(mB + mf * 16 + i) * 1024 + nB + nf * 16] = (bf16)fast_tanh(acc[mf][nf][i]);
}

// s0 = tanh(h0 @ w_init_s^T + b_init_s) -> packed f32 + packed bf16 (M=128)
__global__ __launch_bounds__(256) void kGemmS0(const bf16* __restrict__ Ap,
                                               const bf16* __restrict__ Bp,
                                               const float* __restrict__ bias,
                                               float* sF, bf16* sB) {
  const int nt = blockIdx.x & 15, mt = blockIdx.x >> 4;
  v4f acc[2][2] = {};
  gemmTile<32>(Ap, Bp, mt * 64, nt * 64, 0, acc);
  const int lane = threadIdx.x & 63, w = threadIdx.x >> 6;
  const int wr = w >> 1, wc = w & 1;
  const int mB = mt * 64 + wr * 32 + (lane >> 4) * 4;
  const int nB = nt * 64 + wc * 32 + (lane & 15);
#pragma unroll
  for (int mf = 0; mf < 2; mf++)
#pragma unroll
    for (int nf = 0; nf < 2; nf++) {
      const int n = nB + nf * 16;
      float bv = bias[n];
#pragma unroll
      for (int i = 0; i < 4; i++) {
        const int m = mB + mf * 16 + i;
        float v = fast_tanh(acc[mf][nf][i] + bv);
        size_t pi = packOff(m, n);
        sF[pi] = v;
        sB[pi] = (bf16)v;
      }
    }
}

// [pres|sa|gh] partials = s0 @ WP5^T, K-split x2 (grid 320) — setup only
__global__ __launch_bounds__(256) void kGemmPS(const bf16* __restrict__ Ap,
                                               const bf16* __restrict__ Bp,
                                               float* PS0, float* PS1) {
  const int t = blockIdx.x;
  const int kh = t & 1, mh = (t >> 1) & 1, nt = t >> 2;
  v4f acc[2][2] = {};
  gemmTile<16>(Ap, Bp, mh * 64, nt * 64, kh * 16, acc);
  storeTileF32(kh ? PS1 : PS0, 5120, mh * 64, nt * 64, acc);
}

// ---------------------------------------------------------------------------
// Software grid barrier: monotonic counter, agent scope. Release fence drains
// this XCD's writes to the device-coherent point; acquire fence invalidates
// L1/L2 so post-barrier loads see other XCDs' data (G16). Bounded spin so a
// co-residency failure shows up as a wrong answer, not a harness timeout.
// ---------------------------------------------------------------------------
static __device__ __forceinline__ void gridBarrier(unsigned* bar, unsigned target) {
  __syncthreads();
  if (threadIdx.x == 0) {
    __threadfence();   // release
    __hip_atomic_fetch_add(bar, 1u, __ATOMIC_RELAXED, __HIP_MEMORY_SCOPE_AGENT);
    unsigned tries = 0;
    while (__hip_atomic_load(bar, __ATOMIC_RELAXED, __HIP_MEMORY_SCOPE_AGENT) < target) {
      __builtin_amdgcn_s_sleep(2);
      if (++tries > 100000000u) break;   // ~5s safety valve
    }
    __threadfence();   // acquire
  }
  __syncthreads();
  __asm__ volatile("" ::: "memory");   // no load caching across the barrier
}

// Output phase for step `step` (verified round 3)
static __device__ __forceinline__ void outPhase(
    int b, int step,
    const float* PS0, const float* PS1,
    const float* gcp0, const float* gcp1,
    const float* ygp, const float* __restrict__ bsum,
    float* out, bf16* y_b16p, float* smred) {
  const int tid = threadIdx.x, lane = tid & 63, w = tid >> 6;
  const int v0 = tid * 4;
  const size_t o5 = (size_t)b * 5120 + v0;
  const size_t o4 = (size_t)b * 4096 + 3072 + v0;
  v4f pre = *(const v4f*)(PS0 + o5);
  pre += *(const v4f*)(PS1 + o5);
  pre += *(const v4f*)(gcp0 + o4);
  pre += *(const v4f*)(gcp1 + o4);
  pre += *(const v4f*)(ygp + o4);
  pre += *(const v4f*)(bsum + v0);
  float ee[4];
  float psum = 0.f;
#pragma unroll
  for (int i = 0; i < 4; i++) { ee[i] = __expf(fast_tanh(pre[i])); psum += ee[i]; }
#pragma unroll
  for (int off = 32; off; off >>= 1) psum += __shfl_down(psum, off, 64);
  if (lane == 0) smred[w] = psum;
  __syncthreads();
  const float rden = __builtin_amdgcn_rcpf(smred[0] + smred[1] + smred[2] + smred[3]);
  v4f y4;
#pragma unroll
  for (int i = 0; i < 4; i++) y4[i] = ee[i] * rden;
  *(v4f*)(out + ((size_t)b * 128 + step) * 1024 + v0) = y4;
  *(v4bf*)(y_b16p + packOff(b, v0)) = __builtin_convertvector(y4, v4bf);
}

// ---------------------------------------------------------------------------
// Persistent step kernel: 320 wgs x 256 thr, plain launch (NOT cooperative).
// Co-residency: __launch_bounds__(256,2) caps VGPR<=256 -> >=2 blocks/CU ->
// capacity >=512 >= 320. 5 phases / 5 grid barriers per step.
// ---------------------------------------------------------------------------
__global__ __launch_bounds__(256, 2) void kStep(
    const bf16* __restrict__ twb, const bf16* __restrict__ hb,
    const float* __restrict__ b_s_a, const float* __restrict__ w_a,
    const float* __restrict__ gru_b_ih, const float* __restrict__ gru_b_hh,
    const float* __restrict__ bsum,
    const bf16* __restrict__ W2p, const bf16* __restrict__ W3p,
    const bf16* __restrict__ WP5p,
    float* PS0, float* PS1, float* gcp0, float* gcp1, float* ygp,
    float* esh_g, float* s_f32p,
    bf16* s_b16p, bf16* y_b16p, bf16* c_b16p,
    float* out, unsigned* bar)
{
  __shared__ float sm[2052];
  const int wg = blockIdx.x;
  const int tid = threadIdx.x, lane = tid & 63, w = tid >> 6;
  unsigned gen = 0;

  // Hoist static per-lane score constants (w_a never changes)
  float wj[16];
  const bf16* twB0 = nullptr;
  if (wg < 256) {
    const int b = wg >> 1, half = wg & 1;
    const int h0 = lane * 16;
#pragma unroll
    for (int j = 0; j < 16; j++) wj[j] = w_a[h0 + j];
    twB0 = twb + ((size_t)b * 256 + half * 128 + w * 32) * 1024 + h0;
  }

#pragma unroll 1
  for (int step = 0; step < 128; step++) {
    // ---- P1: scores (wg<256: 2 wgs/b) || out for step-1 (wg>=256: 2 b each) ----
    if (wg < 256) {
      const int b = wg >> 1;
      float* ts = sm;
#pragma unroll
      for (int jj = 0; jj < 4; jj++) {
        int j = tid + jj * 256;
        float sa = PS0[(size_t)b * 5120 + 1024 + j] + PS1[(size_t)b * 5120 + 1024 + j] + b_s_a[j];
        float t = fast_tanh(sa);
        ts[j] = fminf(fmaxf(t, -0.99999994f), 0.99999994f);  // identity denom != 0
      }
      __syncthreads();
      float tj[16];
      const int h0 = lane * 16;
#pragma unroll
      for (int j = 0; j < 16; j++) tj[j] = ts[h0 + j];
      // tanh(a+b) = (tanh a + tanh b)/(1 + tanh a tanh b); tw = tanh(wh) precomputed
      for (int ti = 0; ti < 32; ti++) {
        const bf16* p = twB0 + (size_t)ti * 1024;
        v8bf t8a = *(const v8bf*)p;
        v8bf t8b = *(const v8bf*)(p + 8);
        float acc = 0.f;
#pragma unroll
        for (int j = 0; j < 8; j++) {
          float tv = (float)t8a[j];
          acc += wj[j] * (tv + tj[j]) * __builtin_amdgcn_rcpf(__builtin_fmaf(tv, tj[j], 1.f));
          float tv2 = (float)t8b[j];
          acc += wj[8 + j] * (tv2 + tj[8 + j]) * __builtin_amdgcn_rcpf(__builtin_fmaf(tv2, tj[8 + j], 1.f));
        }
#pragma unroll
        for (int off = 32; off; off >>= 1) acc += __shfl_down(acc, off, 64);
        if (lane == 0) esh_g[(size_t)(wg >> 1) * 256 + (wg & 1) * 128 + w * 32 + ti] = __expf(acc);
      }
      __syncthreads();
    } else if (step > 0) {
#pragma unroll 1
      for (int bb = 0; bb < 2; bb++) {
        outPhase((wg - 256) * 2 + bb, step - 1, PS0, PS1, gcp0, gcp1, ygp, bsum,
                 out, y_b16p, sm);
        __syncthreads();
      }
    }
    gridBarrier(bar, (++gen) * 320u);

    // ---- P2: context (wg<128) || ygp = y @ W2^T (wg 128..255) ----
    if (wg < 128) {
      const int b = wg;
      float ev = esh_g[(size_t)b * 256 + tid];
      sm[tid] = ev;
      float p = ev;
#pragma unroll
      for (int off = 32; off; off >>= 1) p += __shfl_down(p, off, 64);
      if (lane == 0) sm[1024 + w] = p;
      __syncthreads();
      const float rden = __builtin_amdgcn_rcpf(sm[1024] + sm[1025] + sm[1026] + sm[1027]);
      const int d0 = tid * 4;
      const bf16* hp = hb + (size_t)b * 262144 + d0;
      v4f cacc = {};
#pragma unroll 8
      for (int t = 0; t < 256; t++) {
        v4bf h4 = *(const v4bf*)hp;
        hp += 1024;
        cacc += sm[t] * __builtin_convertvector(h4, v4f);
      }
      cacc *= rden;
      *(v4bf*)(c_b16p + packOff(b, d0)) = __builtin_convertvector(cacc, v4bf);
      __syncthreads();
    } else if (wg < 256) {
      const int tile = wg - 128;
      const int nt = tile & 63, mh = tile >> 6;
      v4f acc[2][2] = {};
      gemmTile<32>(y_b16p, W2p, mh * 64, nt * 64, 0, acc);
      storeTileF32(ygp, 4096, mh * 64, nt * 64, acc);
    }
    gridBarrier(bar, (++gen) * 320u);

    // ---- P3: gcp partials = c @ W3^T, K-split x2 (wg<256, 1:1) ----
    if (wg < 256) {
      const int kh = wg & 1, mh = (wg >> 1) & 1, nt = wg >> 2;
      v4f acc[2][2] = {};
      gemmTile<16>(c_b16p, W3p, mh * 64, nt * 64, kh * 16, acc);
      storeTileF32(kh ? gcp1 : gcp0, 4096, mh * 64, nt * 64, acc);
    }
    gridBarrier(bar, (++gen) * 320u);

    // ---- P4: GRU pointwise -> s_new (wg<64, 16384 threads) ----
    if (wg < 64) {
      const int th = wg * 256 + tid;
      const int rb = th >> 11, ks = (th >> 6) & 31, l = th & 63;
      const int r = rb * 16 + (l & 15);
      const int j0 = ks * 32 + ((l >> 4) & 3) * 8;
      const float* g0 = gcp0 + (size_t)r * 4096 + j0;
      const float* g1 = gcp1 + (size_t)r * 4096 + j0;
      const float* yg = ygp + (size_t)r * 4096 + j0;
      const float* p0 = PS0 + (size_t)r * 5120 + j0;
      const float* p1 = PS1 + (size_t)r * 5120 + j0;
      const float* bih = gru_b_ih + j0;
      const float* bhh = gru_b_hh + j0;
      float sv[8], sn[8];
      *(v4f*)sv = *(const v4f*)(s_f32p + (size_t)th * 8);
      *(v4f*)(sv + 4) = *(const v4f*)(s_f32p + (size_t)th * 8 + 4);
#pragma unroll
      for (int e = 0; e < 8; e++) {
        float ir  = g0[e] + g1[e] + yg[e] + bih[e];
        float iz  = g0[1024 + e] + g1[1024 + e] + yg[1024 + e] + bih[1024 + e];
        float in_ = g0[2048 + e] + g1[2048 + e] + yg[2048 + e] + bih[2048 + e];
        float hr = p0[2048 + e] + p1[2048 + e] + bhh[e];
        float hz = p0[3072 + e] + p1[3072 + e] + bhh[1024 + e];
        float hn = p0[4096 + e] + p1[4096 + e] + bhh[2048 + e];
        float rg = fast_sigmoid(ir + hr);
        float zg = fast_sigmoid(iz + hz);
        float ng = fast_tanh(in_ + rg * hn);
        sn[e] = (1.f - zg) * ng + zg * sv[e];
      }
      *(v4f*)(s_f32p + (size_t)th * 8) = *(v4f*)sn;
      *(v4f*)(s_f32p + (size_t)th * 8 + 4) = *(v4f*)(sn + 4);
      v8bf sb;
#pragma unroll
      for (int e = 0; e < 8; e++) sb[e] = (bf16)sn[e];
      *(v8bf*)(s_b16p + (size_t)th * 8) = sb;
    }
    gridBarrier(bar, (++gen) * 320u);

    // ---- P5: [pres|sa'|gh'] partials = s_new @ WP5^T, K-split (320 tiles 1:1) ----
    {
      const int kh = wg & 1, mh = (wg >> 1) & 1, nt = wg >> 2;
      v4f acc[2][2] = {};
      gemmTile<16>(s_b16p, WP5p, mh * 64, nt * 64, kh * 16, acc);
      storeTileF32(kh ? PS1 : PS0, 5120, mh * 64, nt * 64, acc);
    }
    gridBarrier(bar, (++gen) * 320u);
  }

  // ---- tail: out for step 127 ----
  if (wg < 128) outPhase(wg, 127, PS0, PS1, gcp0, gcp1, ygp, bsum, out, y_b16p, sm);
}

// ---------------------------------------------------------------------------
extern "C" void kernel_launch(void* const* d_in, const int* in_sizes, int n_in,
                              void* d_out, int out_size, void* d_ws, size_t ws_size,
                              hipStream_t stream) {
  const float* h        = (const float*)d_in[0];
  const float* w_h_a    = (const float*)d_in[1];
  const float* w_s_a    = (const float*)d_in[2];
  const float* b_s_a    = (const float*)d_in[3];
  const float* w_a      = (const float*)d_in[4];
  const float* w_init_s = (const float*)d_in[5];
  const float* b_init_s = (const float*)d_in[6];
  const float* gru_w_ih = (const float*)d_in[7];
  const float* gru_w_hh = (const float*)d_in[8];
  const float* gru_b_ih = (const float*)d_in[9];
  const float* gru_b_hh = (const float*)d_in[10];
  const float* rnn_w_ih = (const float*)d_in[11];
  const float* rnn_w_hh = (const float*)d_in[12];
  const float* rnn_b_ih = (const float*)d_in[13];
  const float* rnn_b_hh = (const float*)d_in[14];
  (void)in_sizes; (void)n_in; (void)out_size; (void)ws_size;

  char* p = (char*)d_ws;
  auto alloc = [&](size_t bytes) { char* r = p; p += (bytes + 255) & ~(size_t)255; return r; };
  bf16* hbig   = (bf16*)alloc(33554432ull * 2);   // packed h (setup), then linear bf16 h
  bf16* twb    = (bf16*)alloc(33554432ull * 2);   // tanh(h@w_h_a^T), linear
  bf16* h0p    = (bf16*)alloc(131072ull * 2);     // packed h[:,0,:]
  bf16* wbha_p = (bf16*)alloc(1048576ull * 2);
  bf16* wbini_p= (bf16*)alloc(1048576ull * 2);
  bf16* W2p    = (bf16*)alloc(4194304ull * 2);    // [gru_w_ih[:,1024:]; rnn_w_hh] packed
  bf16* W3p    = (bf16*)alloc(4194304ull * 2);    // [gru_w_ih[:,:1024]; rnn_w_ih[:,:1024]] packed
  bf16* WP5p   = (bf16*)alloc(5242880ull * 2);    // [rnn_w_ih[:,1024:]; w_s_a; gru_w_hh] packed
  float* PS0   = (float*)alloc(128ull * 5120 * 4);
  float* PS1   = (float*)alloc(128ull * 5120 * 4);
  float* gcp0  = (float*)alloc(128ull * 4096 * 4);
  float* gcp1  = (float*)alloc(128ull * 4096 * 4);
  float* ygp   = (float*)alloc(128ull * 4096 * 4);
  float* esh_g = (float*)alloc(128ull * 256 * 4);
  float* s_f32p= (float*)alloc(131072ull * 4);
  float* bsum  = (float*)alloc(1024ull * 4);
  bf16* s_b16p = (bf16*)alloc(131072ull * 2);
  bf16* y_b16p = (bf16*)alloc(131072ull * 2);
  bf16* c_b16p = (bf16*)alloc(131072ull * 2);
  unsigned* bar = (unsigned*)alloc(256);
  float* out = (float*)d_out;

  // ---- setup: pack everything into MFMA-fragment order ----
  kPack<<<dim3(16384), 256, 0, stream>>>(h, 1024, hbig, 4194304);          // h packed (for tw GEMM)
  kPack<<<dim3(64),    256, 0, stream>>>(h, 262144, h0p, 16384);           // h[:,0,:]
  kPack<<<dim3(512),   256, 0, stream>>>(w_h_a, 1024, wbha_p, 131072);
  kPack<<<dim3(512),   256, 0, stream>>>(w_init_s, 1024, wbini_p, 131072);
  kPack<<<dim3(1536),  256, 0, stream>>>(gru_w_ih, 2048, W3p, 393216);                  // rows 0..3071
  kPack<<<dim3(512),   256, 0, stream>>>(rnn_w_ih, 2048, W3p + 3145728, 131072);        // rows 3072..4095
  kPack<<<dim3(1536),  256, 0, stream>>>(gru_w_ih + 1024, 2048, W2p, 393216);
  kPack<<<dim3(512),   256, 0, stream>>>(rnn_w_hh, 1024, W2p + 3145728, 131072);
  kPack<<<dim3(512),   256, 0, stream>>>(rnn_w_ih + 1024, 2048, WP5p, 131072);          // rows 0..1023
  kPack<<<dim3(512),   256, 0, stream>>>(w_s_a, 1024, WP5p + 1048576, 131072);          // rows 1024..2047
  kPack<<<dim3(1536),  256, 0, stream>>>(gru_w_hh, 1024, WP5p + 2097152, 393216);       // rows 2048..5119
  kPrep<<<dim3(69), 256, 0, stream>>>(rnn_b_ih, rnn_b_hh, bsum, y_b16p, bar);

  // tw = tanh(h @ w_h_a^T) (M=32768) using packed h; then repurpose hbig as
  // LINEAR bf16 h for the context phase.
  kGemmTW<<<dim3(8192), 256, 0, stream>>>(hbig, wbha_p, twb);
  kCast4<<<dim3(32768), 256, 0, stream>>>(h, hbig, 8388608);
  // s0, then PS init = s0 @ WP5^T (K-split partials)
  kGemmS0<<<dim3(32), 256, 0, stream>>>(h0p, wbini_p, b_init_s, s_f32p, s_b16p);
  kGemmPS<<<dim3(320), 256, 0, stream>>>(s_b16p, WP5p, PS0, PS1);

  // ---- all 128 decode steps: ONE persistent kernel, plain launch ----
  kStep<<<dim3(320), 256, 0, stream>>>(twb, hbig, b_s_a, w_a, gru_b_ih, gru_b_hh,
                                       bsum, W2p, W3p, WP5p,
                                       PS0, PS1, gcp0, gcp1, ygp, esh_g, s_f32p,
                                       s_b16p, y_b16p, c_b16p, out, bar);
}